// Round 1
// baseline (123.185 us; speedup 1.0000x reference)
//
#include <hip/hip_runtime.h>
#include <hip/hip_bf16.h>
#include <stdint.h>

#define BDIM 256

typedef __attribute__((ext_vector_type(8))) short short8;
typedef __attribute__((ext_vector_type(4))) float f32x4;
typedef __attribute__((ext_vector_type(4))) unsigned int u32x4;

__device__ __forceinline__ unsigned short f2bf(float f) {
  union { float f; unsigned u; } v; v.f = f;
  unsigned r = v.u + 0x7fffu + ((v.u >> 16) & 1u);  // round-to-nearest-even
  return (unsigned short)(r >> 16);
}
__device__ __forceinline__ float bf2f(unsigned short u) {
  union { unsigned u; float f; } v; v.u = ((unsigned)u) << 16;
  return v.f;
}

// ---- weight conversion: W1 [1024,676] -> bf16 [1024,704] zero-padded K ----
__global__ __launch_bounds__(BDIM) void cast_pad_w1(const float* __restrict__ w,
                                                    unsigned short* __restrict__ o) {
  int idx = blockIdx.x * BDIM + threadIdx.x;
  if (idx >= 1024 * 704) return;
  int n = idx / 704, k = idx - n * 704;
  float v = (k < 676) ? w[n * 676 + k] : 0.f;
  o[idx] = f2bf(v);
}

__global__ __launch_bounds__(BDIM) void cast_plain(const float* __restrict__ w,
                                                   unsigned short* __restrict__ o, int count) {
  int idx = blockIdx.x * BDIM + threadIdx.x;
  if (idx < count) o[idx] = f2bf(w[idx]);
}

// ---- conv 3x3 VALID, 28x28 -> 26x26, f32 compute, bf16 out padded 676->704 ----
__global__ __launch_bounds__(BDIM) void conv3x3(const float* __restrict__ x,
                                                const float* __restrict__ cw,
                                                unsigned short* __restrict__ h0) {
  __shared__ float xs[784];
  __shared__ float w[9];
  int m = blockIdx.x;
  const float* xr = x + (size_t)m * 784;
  if (threadIdx.x < 9) w[threadIdx.x] = cw[threadIdx.x];
  for (int i = threadIdx.x; i < 784; i += BDIM) xs[i] = xr[i];
  __syncthreads();
  unsigned short* hr = h0 + (size_t)m * 704;
  for (int p = threadIdx.x; p < 704; p += BDIM) {
    float v = 0.f;
    if (p < 676) {
      int r = p / 26, c = p - r * 26;
      const float* xp = &xs[r * 28 + c];
      v = xp[0]  * w[0] + xp[1]  * w[1] + xp[2]  * w[2]
        + xp[28] * w[3] + xp[29] * w[4] + xp[30] * w[5]
        + xp[56] * w[6] + xp[57] * w[7] + xp[58] * w[8];
    }
    hr[p] = f2bf(v);
  }
}

// ---- C[m,n] = act(sum_k A[m,k] * Wt[n,k] + bias[n]) -> bf16 ----
// A [M,K] bf16 row-major, Wt [N,K] bf16 row-major. 128x128 tile, BK=32,
// 4 waves each computing a 64x64 quadrant via 4x4 of 16x16x32 MFMA.
template <bool RELU>
__global__ __launch_bounds__(BDIM) void gemm_bt(const unsigned short* __restrict__ A,
                                                const unsigned short* __restrict__ Wt,
                                                const float* __restrict__ bias,
                                                unsigned short* __restrict__ Cb,
                                                int M, int N, int K) {
  __shared__ unsigned short As[128 * 32];
  __shared__ unsigned short Bs[128 * 32];
  const int tid = threadIdx.x;
  const int lane = tid & 63;
  const int wid = tid >> 6;
  const int nbm = M >> 7;
  const int brow = (blockIdx.x % nbm) << 7;
  const int bcol = (blockIdx.x / nbm) << 7;

  // staging: thread t covers flat elems [t*8, t*8+8) and [2048 + t*8, ...)
  const int r0 = tid >> 2;             // row of chunk0
  const int c0 = (tid & 3) * 8;        // col of chunk
  const int r1 = r0 + 64;              // row of chunk1
  const unsigned short* gA0 = A + (size_t)(brow + r0) * K + c0;
  const unsigned short* gA1 = A + (size_t)(brow + r1) * K + c0;
  const unsigned short* gB0 = Wt + (size_t)(bcol + r0) * K + c0;
  const unsigned short* gB1 = Wt + (size_t)(bcol + r1) * K + c0;
  unsigned short* sA0 = As + tid * 8;
  unsigned short* sA1 = As + 2048 + tid * 8;
  unsigned short* sB0 = Bs + tid * 8;
  unsigned short* sB1 = Bs + 2048 + tid * 8;

  u32x4 ra0 = *(const u32x4*)gA0, ra1 = *(const u32x4*)gA1;
  u32x4 rb0 = *(const u32x4*)gB0, rb1 = *(const u32x4*)gB1;

  f32x4 acc[4][4] = {};

  const int wr = (wid >> 1) << 6;      // wave row offset in tile (0/64)
  const int wc = (wid & 1) << 6;       // wave col offset in tile (0/64)
  const int fr = lane & 15;            // fragment row/col within 16
  const int fk = (lane >> 4) << 3;     // k-group offset (0/8/16/24)
  const unsigned short* pa = As + (wr + fr) * 32 + fk;
  const unsigned short* pb = Bs + (wc + fr) * 32 + fk;

  const int nk = K >> 5;
  for (int kt = 0; kt < nk; ++kt) {
    __syncthreads();                    // previous reads done
    *(u32x4*)sA0 = ra0; *(u32x4*)sA1 = ra1;
    *(u32x4*)sB0 = rb0; *(u32x4*)sB1 = rb1;
    __syncthreads();                    // writes visible
    if (kt + 1 < nk) {                  // prefetch next K-tile (overlaps MFMA)
      gA0 += 32; gA1 += 32; gB0 += 32; gB1 += 32;
      ra0 = *(const u32x4*)gA0; ra1 = *(const u32x4*)gA1;
      rb0 = *(const u32x4*)gB0; rb1 = *(const u32x4*)gB1;
    }
    short8 af[4], bf[4];
#pragma unroll
    for (int m = 0; m < 4; ++m) af[m] = *(const short8*)(pa + m * 512);
#pragma unroll
    for (int n = 0; n < 4; ++n) bf[n] = *(const short8*)(pb + n * 512);
#pragma unroll
    for (int m = 0; m < 4; ++m)
#pragma unroll
      for (int n = 0; n < 4; ++n)
        acc[m][n] = __builtin_amdgcn_mfma_f32_16x16x32_bf16(af[m], bf[n], acc[m][n], 0, 0, 0);
  }

  // epilogue: C[(l>>4)*4+j][l&15] per fragment (m89/m91-verified layout)
  const int crow = brow + wr + ((lane >> 4) << 2);
  const int ccol0 = bcol + wc + (lane & 15);
#pragma unroll
  for (int n = 0; n < 4; ++n) {
    const int cc = ccol0 + n * 16;
    const float bv = bias[cc];
#pragma unroll
    for (int m = 0; m < 4; ++m) {
      const int rr = crow + m * 16;
#pragma unroll
      for (int j = 0; j < 4; ++j) {
        float v = acc[m][n][j] + bv;
        if (RELU) v = v > 0.f ? v : 0.f;
        Cb[(size_t)(rr + j) * N + cc] = f2bf(v);
      }
    }
  }
}

// ---- final layer: out[m,n] = sum_k h3[m,k]*W4[n,k] + b4[n], N=10, K=256, f32 out ----
__global__ __launch_bounds__(BDIM) void fc10(const unsigned short* __restrict__ h3,
                                             const float* __restrict__ W4,
                                             const float* __restrict__ b4,
                                             float* __restrict__ out) {
  int lane = threadIdx.x & 63;
  int wid = threadIdx.x >> 6;
  int m = blockIdx.x * 4 + wid;
  const unsigned short* hr = h3 + (size_t)m * 256 + lane * 4;
  uint64_t hv = *(const uint64_t*)hr;
  float e0 = bf2f((unsigned short)hv), e1 = bf2f((unsigned short)(hv >> 16));
  float e2 = bf2f((unsigned short)(hv >> 32)), e3 = bf2f((unsigned short)(hv >> 48));
#pragma unroll
  for (int n = 0; n < 10; ++n) {
    const float4 wv = *(const float4*)(W4 + n * 256 + lane * 4);
    float s = e0 * wv.x + e1 * wv.y + e2 * wv.z + e3 * wv.w;
#pragma unroll
    for (int off = 32; off > 0; off >>= 1) s += __shfl_xor(s, off);
    if (lane == n) out[(size_t)m * 10 + n] = s + b4[n];
  }
}

extern "C" void kernel_launch(void* const* d_in, const int* in_sizes, int n_in,
                              void* d_out, int out_size, void* d_ws, size_t ws_size,
                              hipStream_t stream) {
  const float* x  = (const float*)d_in[0];
  const float* cw = (const float*)d_in[1];
  const float* W1 = (const float*)d_in[2];
  const float* b1 = (const float*)d_in[3];
  const float* W2 = (const float*)d_in[4];
  const float* b2 = (const float*)d_in[5];
  const float* W3 = (const float*)d_in[6];
  const float* b3 = (const float*)d_in[7];
  const float* W4 = (const float*)d_in[8];
  const float* b4 = (const float*)d_in[9];
  float* out = (float*)d_out;

  char* ws = (char*)d_ws;
  // h0 [16384,704] bf16 (23,068,672 B) — region reused for h2 [16384,512]
  // h1 [16384,1024] bf16 (33,554,432 B) — region reused for h3 [16384,256]
  unsigned short* h0  = (unsigned short*)(ws);
  unsigned short* h1  = (unsigned short*)(ws + 23068672);
  unsigned short* W1b = (unsigned short*)(ws + 23068672 + 33554432);
  unsigned short* W2b = W1b + 1024 * 704;
  unsigned short* W3b = W2b + 512 * 1024;
  unsigned short* h2  = h0;
  unsigned short* h3  = h1;

  cast_pad_w1<<<2816, BDIM, 0, stream>>>(W1, W1b);
  cast_plain<<<2048, BDIM, 0, stream>>>(W2, W2b, 512 * 1024);
  cast_plain<<<512, BDIM, 0, stream>>>(W3, W3b, 256 * 512);
  conv3x3<<<16384, BDIM, 0, stream>>>(x, cw, h0);

  gemm_bt<true><<<(16384 / 128) * (1024 / 128), BDIM, 0, stream>>>(h0, W1b, b1, h1, 16384, 1024, 704);
  gemm_bt<true><<<(16384 / 128) * (512 / 128),  BDIM, 0, stream>>>(h1, W2b, b2, h2, 16384, 512, 1024);
  gemm_bt<true><<<(16384 / 128) * (256 / 128),  BDIM, 0, stream>>>(h2, W3b, b3, h3, 16384, 256, 512);
  fc10<<<16384 / 4, BDIM, 0, stream>>>(h3, W4, b4, out);
}